// Round 8
// baseline (3373.781 us; speedup 1.0000x reference)
//
#include <hip/hip_runtime.h>

typedef _Float16 f16;
typedef _Float16 f16x8 __attribute__((ext_vector_type(8)));
typedef float f32x4 __attribute__((ext_vector_type(4)));

// async global->LDS, 16B per lane; LDS dest must be linear (base + lane*16).
__device__ __forceinline__ void gload_lds16(const void* g, void* l) {
  __builtin_amdgcn_global_load_lds(
      (const __attribute__((address_space(1))) void*)g,
      (__attribute__((address_space(3))) void*)l, 16, 0, 0);
}

__device__ __forceinline__ float act_apply(float x, int id) {
  switch (id) {
    case 0: return fmaxf(x, 0.0f);
    case 1: return 1.0f / (1.0f + __expf(-x));
    case 2: return tanhf(x);
    case 3: return x >= 0.0f ? x : 0.1f * x;
    default: return 1.0507009873554805f *
                    (x > 0.0f ? x : 1.6732632423543772f * expm1f(x));
  }
}

// ============================================================================
// FLAT: no LDS, no barriers. 128x128 block tile, 4 waves (2x2), 64x64/wave.
// A and B fragments loaded directly global->reg (wave reads contiguous
// 16-row x 64B panels; L1 serves intra-block reuse, L2/L3 inter-block).
// Ping-pong prefetch one K32 ahead; compiler emits counted vmcnt.
// ============================================================================
template <bool FINAL>
__global__ __launch_bounds__(256, 3)
void gemm_flat(const f16* __restrict__ A, const f16* __restrict__ W,
               const float* __restrict__ bias, const int* __restrict__ ids,
               float Sa, float invSn, void* __restrict__ outv,
               int M, int N, int K) {
  const int tid  = (int)threadIdx.x;
  const int lane = tid & 63;
  const int wid  = tid >> 6;           // 0..3
  const int wr   = (wid >> 1) * 64;    // waves {0,1} rows 0-63, {2,3} 64-127
  const int wc   = (wid & 1) * 64;     // waves {0,2} cols 0-63, {1,3} 64-127

  // bijective XCD-aware swizzle (nwg % 8 == 0 for all shapes here)
  const int nbx = N >> 7;
  const int nwg = (M >> 7) * nbx;
  const int b   = (int)blockIdx.x;
  const int swz = (b & 7) * (nwg >> 3) + (b >> 3);
  const int brow = (swz / nbx) << 7;
  const int bcol = (swz % nbx) << 7;

  // fragment addressing: row/col = lane&15, k-offset = 8*(lane>>4)
  const int fr = lane & 15;
  const int k8 = (lane >> 4) << 3;

  const f16* pa[4];
  const f16* pb[4];
#pragma unroll
  for (int m = 0; m < 4; ++m)
    pa[m] = A + (long)(brow + wr + m * 16 + fr) * K + k8;
#pragma unroll
  for (int n = 0; n < 4; ++n)
    pb[n] = W + (long)(bcol + wc + n * 16 + fr) * K + k8;

  f32x4 acc[4][4];
#pragma unroll
  for (int m = 0; m < 4; ++m)
#pragma unroll
    for (int n = 0; n < 4; ++n) acc[m][n] = (f32x4){0.f, 0.f, 0.f, 0.f};

  f16x8 a0[4], b0[4], a1[4], b1[4];
#pragma unroll
  for (int m = 0; m < 4; ++m) a0[m] = *(const f16x8*)(pa[m]);
#pragma unroll
  for (int n = 0; n < 4; ++n) b0[n] = *(const f16x8*)(pb[n]);

  for (long kk = 0; kk < K; kk += 64) {
    // prefetch K-slice kk+32 (always exists: K % 64 == 0)
#pragma unroll
    for (int m = 0; m < 4; ++m) a1[m] = *(const f16x8*)(pa[m] + kk + 32);
#pragma unroll
    for (int n = 0; n < 4; ++n) b1[n] = *(const f16x8*)(pb[n] + kk + 32);

#pragma unroll
    for (int m = 0; m < 4; ++m)
#pragma unroll
      for (int n = 0; n < 4; ++n)
        acc[m][n] = __builtin_amdgcn_mfma_f32_16x16x32_f16(a0[m], b0[n],
                                                           acc[m][n], 0, 0, 0);

    if (kk + 64 < K) {
#pragma unroll
      for (int m = 0; m < 4; ++m) a0[m] = *(const f16x8*)(pa[m] + kk + 64);
#pragma unroll
      for (int n = 0; n < 4; ++n) b0[n] = *(const f16x8*)(pb[n] + kk + 64);
    }

#pragma unroll
    for (int m = 0; m < 4; ++m)
#pragma unroll
      for (int n = 0; n < 4; ++n)
        acc[m][n] = __builtin_amdgcn_mfma_f32_16x16x32_f16(a1[m], b1[n],
                                                           acc[m][n], 0, 0, 0);
  }

  // D layout: row = (lane>>4)*4 + reg, col = lane&15  (m89-verified)
  const int r4 = (lane >> 4) << 2;
#pragma unroll
  for (int n = 0; n < 4; ++n) {
    const int gcol = bcol + wc + n * 16 + fr;
    const float bv = bias[gcol];
    const int id   = ids[gcol];
#pragma unroll
    for (int m = 0; m < 4; ++m) {
      const int grow = brow + wr + m * 16 + r4;
#pragma unroll
      for (int i = 0; i < 4; ++i) {
        const float y = act_apply(acc[m][n][i] * Sa + bv, id);
        if (FINAL) {
          ((float*)outv)[(long)(grow + i) * N + gcol] = y;
        } else {
          ((f16*)outv)[(long)(grow + i) * N + gcol] = (f16)(y * invSn);
        }
      }
    }
  }
}

// ============================================================================
// Variant B (proven r6, 390us): 128x128 tile, BK=32, 2-deep dbuf,
// __syncthreads drain, 4 blocks/CU, swizzled LDS.
// ============================================================================
template <bool FINAL>
__global__ __launch_bounds__(256, 4)
void gemm128(const f16* __restrict__ A, const f16* __restrict__ W,
             const float* __restrict__ bias, const int* __restrict__ ids,
             float Sa, float invSn, void* __restrict__ outv,
             int M, int N, int K) {
  __shared__ f16 lA[2][128 * 32];
  __shared__ f16 lB[2][128 * 32];

  const int tid  = (int)threadIdx.x;
  const int lane = tid & 63;
  const int wid  = tid >> 6;
  const int wr   = (wid >> 1) * 64;
  const int wc   = (wid & 1) * 64;

  const int nbx = N >> 7;
  const int nwg = (M >> 7) * nbx;
  const int b   = (int)blockIdx.x;
  const int swz = (b & 7) * (nwg >> 3) + (b >> 3);
  const int brow = (swz / nbx) << 7;
  const int bcol = (swz % nbx) << 7;

  const int d0 = tid << 4;
  const int d1 = d0 + 4096;
  const int s0 = d0 ^ (((d0 >> 7) & 7) << 4);
  const int s1 = d1 ^ (((d1 >> 7) & 7) << 4);
  const int r0 = s0 >> 6, c0 = (s0 >> 4) & 3;
  const int r1 = s1 >> 6, c1 = (s1 >> 4) & 3;

  const f16* pA0 = A + (long)(brow + r0) * K + c0 * 8;
  const f16* pA1 = A + (long)(brow + r1) * K + c1 * 8;
  const f16* pB0 = W + (long)(bcol + r0) * K + c0 * 8;
  const f16* pB1 = W + (long)(bcol + r1) * K + c1 * 8;
  const int e0 = tid << 3;
  const int e1 = e0 + 2048;

  const int fr = lane & 15;
  const int kb = lane >> 4;
  const int xorv = ((fr >> 1) & 7) << 4;

  int offA[4], offB[4];
#pragma unroll
  for (int m = 0; m < 4; ++m)
    offA[m] = (((wr + m * 16 + fr) << 6) + (kb << 4)) ^ xorv;
#pragma unroll
  for (int n = 0; n < 4; ++n)
    offB[n] = (((wc + n * 16 + fr) << 6) + (kb << 4)) ^ xorv;

  f32x4 acc[4][4];
#pragma unroll
  for (int m = 0; m < 4; ++m)
#pragma unroll
    for (int n = 0; n < 4; ++n) acc[m][n] = (f32x4){0.f, 0.f, 0.f, 0.f};

  const int nt = K >> 5;
  int buf = 0;

  gload_lds16(pA0, &lA[0][e0]);
  gload_lds16(pA1, &lA[0][e1]);
  gload_lds16(pB0, &lB[0][e0]);
  gload_lds16(pB1, &lB[0][e1]);
  __syncthreads();

  for (int t = 0; t < nt; ++t) {
    if (t + 1 < nt) {
      const long kk = (long)(t + 1) << 5;
      gload_lds16(pA0 + kk, &lA[buf ^ 1][e0]);
      gload_lds16(pA1 + kk, &lA[buf ^ 1][e1]);
      gload_lds16(pB0 + kk, &lB[buf ^ 1][e0]);
      gload_lds16(pB1 + kk, &lB[buf ^ 1][e1]);
    }
    const char* bA = (const char*)&lA[buf][0];
    const char* bB = (const char*)&lB[buf][0];
    f16x8 af[4], bf[4];
#pragma unroll
    for (int m = 0; m < 4; ++m) af[m] = *(const f16x8*)(bA + offA[m]);
#pragma unroll
    for (int n = 0; n < 4; ++n) bf[n] = *(const f16x8*)(bB + offB[n]);
#pragma unroll
    for (int m = 0; m < 4; ++m)
#pragma unroll
      for (int n = 0; n < 4; ++n)
        acc[m][n] = __builtin_amdgcn_mfma_f32_16x16x32_f16(af[m], bf[n],
                                                           acc[m][n], 0, 0, 0);
    if (t + 1 < nt) {
      __syncthreads();
      buf ^= 1;
    }
  }

  const int r4 = (lane >> 4) << 2;
#pragma unroll
  for (int n = 0; n < 4; ++n) {
    const int gcol = bcol + wc + n * 16 + fr;
    const float bv = bias[gcol];
    const int id   = ids[gcol];
#pragma unroll
    for (int m = 0; m < 4; ++m) {
      const int grow = brow + wr + m * 16 + r4;
#pragma unroll
      for (int i = 0; i < 4; ++i) {
        const float y = act_apply(acc[m][n][i] * Sa + bv, id);
        if (FINAL) {
          ((float*)outv)[(long)(grow + i) * N + gcol] = y;
        } else {
          ((f16*)outv)[(long)(grow + i) * N + gcol] = (f16)(y * invSn);
        }
      }
    }
  }
}

__global__ void cvt_f32_to_f16(const float* __restrict__ in, f16* __restrict__ out,
                               float scale, int n) {
  int i = ((int)blockIdx.x * 256 + (int)threadIdx.x) * 8;
  const int stride = (int)gridDim.x * 256 * 8;
  for (; i < n; i += stride) {
    const float4 v0 = *(const float4*)(in + i);
    const float4 v1 = *(const float4*)(in + i + 4);
    f16x8 h;
    h[0] = (f16)(v0.x * scale); h[1] = (f16)(v0.y * scale);
    h[2] = (f16)(v0.z * scale); h[3] = (f16)(v0.w * scale);
    h[4] = (f16)(v1.x * scale); h[5] = (f16)(v1.y * scale);
    h[6] = (f16)(v1.z * scale); h[7] = (f16)(v1.w * scale);
    *(f16x8*)(out + i) = h;
  }
}

extern "C" void kernel_launch(void* const* d_in, const int* in_sizes, int n_in,
                              void* d_out, int out_size, void* d_ws, size_t ws_size,
                              hipStream_t stream) {
  (void)in_sizes; (void)n_in; (void)out_size; (void)ws_size;
  const int M = 8192, IND = 2048, HID = 4096, OUTD = 2048;
  const float* x = (const float*)d_in[0];

  f16* actA = (f16*)d_ws;
  f16* actB = actA + (size_t)M * HID;
  f16* wbuf = actB + (size_t)M * HID;

  // static per-layer activation scales (powers of 2, exact)
  const float S[6] = {1.f, 16.f, 512.f, 16384.f, 262144.f, 8388608.f};
  const int Ks[6] = {IND, HID, HID, HID, HID, HID};
  const int Ns[6] = {HID, HID, HID, HID, HID, OUTD};

  cvt_f32_to_f16<<<2048, 256, 0, stream>>>(x, actA, 1.0f, M * IND);

  f16* cur = actA;
  f16* nxt = actB;
  for (int i = 0; i < 6; ++i) {
    const int K = Ks[i], N = Ns[i];
    const float* w  = (const float*)d_in[1 + 3 * i];
    const float* bs = (const float*)d_in[2 + 3 * i];
    const int* id   = (const int*)d_in[3 + 3 * i];

    cvt_f32_to_f16<<<2048, 256, 0, stream>>>(w, wbuf, 1.0f, N * K);

    const int nblk = (M >> 7) * (N >> 7);
    // A/B fork: layers 0-2 -> gemm_flat (no-LDS), 3-5 -> gemm128 (proven).
    // Layers 1,2 vs 3,4 are identical 4096^2 shapes for a clean comparison.
    if (i < 3) {
      gemm_flat<false><<<nblk, 256, 0, stream>>>(
          cur, wbuf, bs, id, S[i], 1.0f / S[i + 1], nxt, M, N, K);
      f16* t = cur; cur = nxt; nxt = t;
    } else if (i < 5) {
      gemm128<false><<<nblk, 256, 0, stream>>>(
          cur, wbuf, bs, id, S[i], 1.0f / S[i + 1], nxt, M, N, K);
      f16* t = cur; cur = nxt; nxt = t;
    } else {
      gemm128<true><<<nblk, 256, 0, stream>>>(
          cur, wbuf, bs, id, S[i], 1.0f, d_out, M, N, K);
    }
  }
}

// Round 9
// 1928.163 us; speedup vs baseline: 1.7497x; 1.7497x over previous
//
#include <hip/hip_runtime.h>

typedef _Float16 f16;
typedef _Float16 f16x8 __attribute__((ext_vector_type(8)));
typedef float f32x4 __attribute__((ext_vector_type(4)));

// async global->LDS, 16B per lane; LDS dest must be linear (base + lane*16).
__device__ __forceinline__ void gload_lds16(const void* g, void* l) {
  __builtin_amdgcn_global_load_lds(
      (const __attribute__((address_space(1))) void*)g,
      (__attribute__((address_space(3))) void*)l, 16, 0, 0);
}

__device__ __forceinline__ float act_apply(float x, int id) {
  switch (id) {
    case 0: return fmaxf(x, 0.0f);
    case 1: return 1.0f / (1.0f + __expf(-x));
    case 2: return tanhf(x);
    case 3: return x >= 0.0f ? x : 0.1f * x;
    default: return 1.0507009873554805f *
                    (x > 0.0f ? x : 1.6732632423543772f * expm1f(x));
  }
}

// ============================================================================
// gemm128 (proven r6 core): 128x128 tile, BK=32, 2-deep dbuf, __syncthreads
// drain, 4 blocks/CU, zero-conflict swizzled LDS.
// New in r9: (1) 2D-chunked XCD mapping (W-panel L2 residency),
//            (2) LDS-transpose coalesced f16 epilogue.
// ============================================================================
template <bool FINAL>
__global__ __launch_bounds__(256, 4)
void gemm128(const f16* __restrict__ A, const f16* __restrict__ W,
             const float* __restrict__ bias, const int* __restrict__ ids,
             float Sa, float invSn, void* __restrict__ outv,
             int M, int N, int K) {
  __shared__ f16 lA[2][128 * 32];   // 2 x 8 KiB
  __shared__ f16 lB[2][128 * 32];   // 2 x 8 KiB  (32 KiB total)

  const int tid  = (int)threadIdx.x;
  const int lane = tid & 63;
  const int wid  = tid >> 6;   // 0..3
  const int wr   = (wid >> 1) * 64;
  const int wc   = (wid & 1) * 64;

  // ---- 2D-chunked XCD mapping ----
  // XCD x owns a (CR x CC) chunk of the block grid; inner order is
  // column-major so consecutive blocks on an XCD share one W-panel (L2-hot).
  // nbr = 64 always (M=8192). nbc >= 32: 4x2 chunk grid (CR=16).
  // nbc == 16 (final layer): 8x1 chunk grid (CR=8).
  const int nbc = N >> 7;
  const int b   = (int)blockIdx.x;
  const int x   = b & 7;
  const int r   = b >> 3;
  int brow, bcol;
  if (nbc >= 32) {
    brow = ((x >> 1) * 16 + (r & 15)) << 7;   // CR = 16 (nbr/4)
    bcol = ((x & 1) * (nbc >> 1) + (r >> 4)) << 7;
  } else {
    brow = (x * 8 + (r & 7)) << 7;            // CR = 8 (nbr/8)
    bcol = (r >> 3) << 7;
  }

  // ---- staging: pre-swizzled global source, linear LDS dest (0 conflicts) ----
  const int d0 = tid << 4;
  const int d1 = d0 + 4096;
  const int s0 = d0 ^ (((d0 >> 7) & 7) << 4);
  const int s1 = d1 ^ (((d1 >> 7) & 7) << 4);
  const int r0 = s0 >> 6, c0 = (s0 >> 4) & 3;
  const int r1 = s1 >> 6, c1 = (s1 >> 4) & 3;

  const f16* pA0 = A + (long)(brow + r0) * K + c0 * 8;
  const f16* pA1 = A + (long)(brow + r1) * K + c1 * 8;
  const f16* pB0 = W + (long)(bcol + r0) * K + c0 * 8;
  const f16* pB1 = W + (long)(bcol + r1) * K + c1 * 8;
  const int e0 = tid << 3;
  const int e1 = e0 + 2048;

  const int fr = lane & 15;
  const int kb = lane >> 4;
  const int xorv = ((fr >> 1) & 7) << 4;

  int offA[4], offB[4];
#pragma unroll
  for (int m = 0; m < 4; ++m)
    offA[m] = (((wr + m * 16 + fr) << 6) + (kb << 4)) ^ xorv;
#pragma unroll
  for (int n = 0; n < 4; ++n)
    offB[n] = (((wc + n * 16 + fr) << 6) + (kb << 4)) ^ xorv;

  f32x4 acc[4][4];
#pragma unroll
  for (int m = 0; m < 4; ++m)
#pragma unroll
    for (int n = 0; n < 4; ++n) acc[m][n] = (f32x4){0.f, 0.f, 0.f, 0.f};

  const int nt = K >> 5;
  int buf = 0;

  gload_lds16(pA0, &lA[0][e0]);
  gload_lds16(pA1, &lA[0][e1]);
  gload_lds16(pB0, &lB[0][e0]);
  gload_lds16(pB1, &lB[0][e1]);
  __syncthreads();   // compiler drains vmcnt before s_barrier

  for (int t = 0; t < nt; ++t) {
    if (t + 1 < nt) {
      const long kk = (long)(t + 1) << 5;
      gload_lds16(pA0 + kk, &lA[buf ^ 1][e0]);
      gload_lds16(pA1 + kk, &lA[buf ^ 1][e1]);
      gload_lds16(pB0 + kk, &lB[buf ^ 1][e0]);
      gload_lds16(pB1 + kk, &lB[buf ^ 1][e1]);
    }
    const char* bA = (const char*)&lA[buf][0];
    const char* bB = (const char*)&lB[buf][0];
    f16x8 af[4], bf[4];
#pragma unroll
    for (int m = 0; m < 4; ++m) af[m] = *(const f16x8*)(bA + offA[m]);
#pragma unroll
    for (int n = 0; n < 4; ++n) bf[n] = *(const f16x8*)(bB + offB[n]);
#pragma unroll
    for (int m = 0; m < 4; ++m)
#pragma unroll
      for (int n = 0; n < 4; ++n)
        acc[m][n] = __builtin_amdgcn_mfma_f32_16x16x32_f16(af[m], bf[n],
                                                           acc[m][n], 0, 0, 0);
    if (t + 1 < nt) {
      __syncthreads();
      buf ^= 1;
    }
  }

  // D layout: row = (lane>>4)*4 + reg, col = lane&15  (m89-verified)
  const int r4 = (lane >> 4) << 2;

  if (!FINAL) {
    // ---- LDS-transpose epilogue: coalesced 16B f16 stores ----
    __syncthreads();   // staging LDS is dead; reuse as per-wave 8KB tiles
    f16* eb = (wid < 2) ? &lA[wid][0] : &lB[wid - 2][0];
#pragma unroll
    for (int n = 0; n < 4; ++n) {
      const int gcol = bcol + wc + n * 16 + fr;
      const float bv = bias[gcol];
      const int id   = ids[gcol];
#pragma unroll
      for (int m = 0; m < 4; ++m)
#pragma unroll
        for (int i = 0; i < 4; ++i) {
          const float y = act_apply(acc[m][n][i] * Sa + bv, id);
          eb[(m * 16 + r4 + i) * 64 + n * 16 + fr] = (f16)(y * invSn);
        }
    }
    __syncthreads();   // writes visible (also intra-wave ordering)
    f16* outp = (f16*)outv;
#pragma unroll
    for (int j = 0; j < 8; ++j) {
      const int lrow = j * 8 + (lane >> 3);
      const f16x8 v = *(const f16x8*)&eb[lrow * 64 + (lane & 7) * 8];
      *(f16x8*)&outp[(long)(brow + wr + lrow) * N + bcol + wc + (lane & 7) * 8] = v;
    }
  } else {
    // final layer: fp32 output, scattered dword stores (1 layer only)
#pragma unroll
    for (int n = 0; n < 4; ++n) {
      const int gcol = bcol + wc + n * 16 + fr;
      const float bv = bias[gcol];
      const int id   = ids[gcol];
#pragma unroll
      for (int m = 0; m < 4; ++m) {
        const int grow = brow + wr + m * 16 + r4;
#pragma unroll
        for (int i = 0; i < 4; ++i) {
          const float y = act_apply(acc[m][n][i] * Sa + bv, id);
          ((float*)outv)[(long)(grow + i) * N + gcol] = y;
        }
      }
    }
  }
}

__global__ void cvt_f32_to_f16(const float* __restrict__ in, f16* __restrict__ out,
                               float scale, int n) {
  int i = ((int)blockIdx.x * 256 + (int)threadIdx.x) * 8;
  const int stride = (int)gridDim.x * 256 * 8;
  for (; i < n; i += stride) {
    const float4 v0 = *(const float4*)(in + i);
    const float4 v1 = *(const float4*)(in + i + 4);
    f16x8 h;
    h[0] = (f16)(v0.x * scale); h[1] = (f16)(v0.y * scale);
    h[2] = (f16)(v0.z * scale); h[3] = (f16)(v0.w * scale);
    h[4] = (f16)(v1.x * scale); h[5] = (f16)(v1.y * scale);
    h[6] = (f16)(v1.z * scale); h[7] = (f16)(v1.w * scale);
    *(f16x8*)(out + i) = h;
  }
}

extern "C" void kernel_launch(void* const* d_in, const int* in_sizes, int n_in,
                              void* d_out, int out_size, void* d_ws, size_t ws_size,
                              hipStream_t stream) {
  (void)in_sizes; (void)n_in; (void)out_size; (void)ws_size;
  const int M = 8192, IND = 2048, HID = 4096, OUTD = 2048;
  const float* x = (const float*)d_in[0];

  f16* actA = (f16*)d_ws;
  f16* actB = actA + (size_t)M * HID;
  f16* wbuf = actB + (size_t)M * HID;

  // static per-layer activation scales (powers of 2, exact)
  const float S[6] = {1.f, 16.f, 512.f, 16384.f, 262144.f, 8388608.f};
  const int Ks[6] = {IND, HID, HID, HID, HID, HID};
  const int Ns[6] = {HID, HID, HID, HID, HID, OUTD};

  cvt_f32_to_f16<<<2048, 256, 0, stream>>>(x, actA, 1.0f, M * IND);

  f16* cur = actA;
  f16* nxt = actB;
  for (int i = 0; i < 6; ++i) {
    const int K = Ks[i], N = Ns[i];
    const float* w  = (const float*)d_in[1 + 3 * i];
    const float* bs = (const float*)d_in[2 + 3 * i];
    const int* id   = (const int*)d_in[3 + 3 * i];

    cvt_f32_to_f16<<<2048, 256, 0, stream>>>(w, wbuf, 1.0f, N * K);

    const int nblk = (M >> 7) * (N >> 7);
    if (i < 5) {
      gemm128<false><<<nblk, 256, 0, stream>>>(
          cur, wbuf, bs, id, S[i], 1.0f / S[i + 1], nxt, M, N, K);
      f16* t = cur; cur = nxt; nxt = t;
    } else {
      gemm128<true><<<nblk, 256, 0, stream>>>(
          cur, wbuf, bs, id, S[i], 1.0f, d_out, M, N, K);
    }
  }
}